// Round 14
// baseline (218.028 us; speedup 1.0000x reference)
//
#include <hip/hip_runtime.h>
#include <hip/hip_bf16.h>

typedef __attribute__((ext_vector_type(8))) short bf16x8;
typedef __attribute__((ext_vector_type(4))) float f32x4;
typedef __attribute__((ext_vector_type(16))) float f32x16;
typedef __attribute__((ext_vector_type(4))) unsigned short u16x4;

#define DEVI static __device__ __forceinline__

DEVI float bf2f(unsigned short u) {
    union { unsigned int ui; float f; } c; c.ui = ((unsigned int)u) << 16; return c.f;
}
DEVI unsigned short f2bf(float f) {
    union { float f; unsigned int ui; } c; c.f = f;
    unsigned int u = c.ui;
    u += 0x7FFFu + ((u >> 16) & 1u);
    return (unsigned short)(u >> 16);
}
DEVI unsigned int pk2bf(float a, float b) {   // v_cvt_pk_bf16_f32 via compiler
    union { __hip_bfloat162 h; unsigned int u; } c;
    c.h = __float22bfloat162_rn(make_float2(a, b));
    return c.u;
}

#define NRES 320
#define NN   102400
#define CCH  128
#define NPAD 328

#define LOG2E 1.4426950408889634f
#define QSCALE (0.17677669529663687f * 1.4426950408889634f)

// ---------------- Kernel 1: LayerNorm -> xn(bf16) + bterm (log2e-scaled) ----------------
__global__ __launch_bounds__(256) void k_ln_bias(
    const float* __restrict__ x2d, const float* __restrict__ ln_g,
    const float* __restrict__ ln_b, const float* __restrict__ wb,
    unsigned short* __restrict__ xn, float* __restrict__ bterm)
{
    int wave = threadIdx.x >> 6, lane = threadIdx.x & 63;
    int r = blockIdx.x * 4 + wave;
    int c0 = lane * 2;
    float2 x = *(const float2*)(x2d + (size_t)r * CCH + c0);
    float s = x.x + x.y, sq = x.x * x.x + x.y * x.y;
    #pragma unroll
    for (int m = 1; m < 64; m <<= 1) { s += __shfl_xor(s, m, 64); sq += __shfl_xor(sq, m, 64); }
    float mu = s * (1.0f / 128.0f);
    float var = sq * (1.0f / 128.0f) - mu * mu;
    float rstd = rsqrtf(var + 1e-5f);
    float xn0 = (x.x - mu) * rstd * ln_g[c0] + ln_b[c0];
    float xn1 = (x.y - mu) * rstd * ln_g[c0 + 1] + ln_b[c0 + 1];
    *(unsigned int*)(xn + (size_t)r * CCH + c0) = pk2bf(xn0, xn1);
    float4 w0 = *(const float4*)(wb + c0 * 4);
    float4 w1 = *(const float4*)(wb + c0 * 4 + 4);
    float b0 = xn0 * w0.x + xn1 * w1.x;
    float b1 = xn0 * w0.y + xn1 * w1.y;
    float b2 = xn0 * w0.z + xn1 * w1.z;
    float b3 = xn0 * w0.w + xn1 * w1.w;
    #pragma unroll
    for (int m = 1; m < 64; m <<= 1) {
        b0 += __shfl_xor(b0, m, 64); b1 += __shfl_xor(b1, m, 64);
        b2 += __shfl_xor(b2, m, 64); b3 += __shfl_xor(b3, m, 64);
    }
    if (lane == 0) {
        bterm[0 * NN + r] = b0 * LOG2E; bterm[1 * NN + r] = b1 * LOG2E;
        bterm[2 * NN + r] = b2 * LOG2E; bterm[3 * NN + r] = b3 * LOG2E;
    }
}

// ---------------- Kernel 2: qkvg = xn @ W[nt] (grid.y = nt; conflict-free B staging) ----------------
__global__ __launch_bounds__(256) void k_proj(
    const unsigned short* __restrict__ xn,
    const float* __restrict__ wq, const float* __restrict__ wk,
    const float* __restrict__ wv, const float* __restrict__ wg,
    const float* __restrict__ bg,
    unsigned short* __restrict__ qkvg)
{
    __shared__ unsigned short A[128][136];
    __shared__ unsigned short Bt[128][136];   // Bt[n][k]
    int m0 = blockIdx.x * 128;
    int nt = blockIdx.y;
    int t = threadIdx.x;
    const float* wsrc = (nt == 0) ? wq : (nt == 1) ? wk : (nt == 2) ? wv : wg;
    #pragma unroll
    for (int it = 0; it < 8; ++it) {
        int idx = it * 256 + t;
        int row = idx >> 4, chunk = idx & 15;
        *(bf16x8*)(&A[row][chunk * 8]) = *(const bf16x8*)(xn + (size_t)(m0 + row) * CCH + chunk * 8);
    }
    {
        int n = t & 127, p = t >> 7;
        const float* col = wsrc + n;
        #pragma unroll
        for (int q = 0; q < 8; ++q) {
            int k0 = p * 64 + q * 8;
            union { unsigned int u[4]; bf16x8 v; } pk;
            #pragma unroll
            for (int z = 0; z < 4; ++z)
                pk.u[z] = pk2bf(col[(size_t)(k0 + 2 * z) * 128], col[(size_t)(k0 + 2 * z + 1) * 128]);
            *(bf16x8*)(&Bt[n][k0]) = pk.v;
        }
    }
    __syncthreads();
    int wave = t >> 6, lane = t & 63;
    int wr = (wave >> 1) * 64, wc = (wave & 1) * 64;
    int li = lane & 15, lk = (lane >> 4) * 8;
    f32x4 acc[4][4] = {};
    #pragma unroll
    for (int kk = 0; kk < 4; ++kk) {
        bf16x8 af[4], bfr[4];
        #pragma unroll
        for (int i = 0; i < 4; ++i) af[i] = *(const bf16x8*)(&A[wr + i * 16 + li][kk * 32 + lk]);
        #pragma unroll
        for (int j = 0; j < 4; ++j) bfr[j] = *(const bf16x8*)(&Bt[wc + j * 16 + li][kk * 32 + lk]);
        __builtin_amdgcn_s_setprio(1);
        #pragma unroll
        for (int i = 0; i < 4; ++i)
            #pragma unroll
            for (int j = 0; j < 4; ++j)
                acc[i][j] = __builtin_amdgcn_mfma_f32_16x16x32_bf16(af[i], bfr[j], acc[i][j], 0, 0, 0);
        __builtin_amdgcn_s_setprio(0);
    }
    int rbase = (lane >> 4) * 4;
    bool isg = (nt == 3), isq = (nt == 0);
    #pragma unroll
    for (int i = 0; i < 4; ++i) {
        #pragma unroll
        for (int j = 0; j < 4; ++j) {
            int col = wc + j * 16 + li;
            int gcol = nt * 128 + col;
            #pragma unroll
            for (int r = 0; r < 4; ++r) {
                int grow = m0 + wr + i * 16 + rbase + r;
                float v = acc[i][j][r];
                if (isg) { v += bg[col]; v = 1.0f / (1.0f + __expf(-v)); }
                if (isq) v *= QSCALE;
                qkvg[(size_t)grow * 512 + gcol] = f2bf(v);
            }
        }
    }
}

// ---------------- Kernel 3: fused attention per (m,h): 32x32 MFMA, lane-local softmax ----------------
__global__ __launch_bounds__(320) void k_attn(
    const unsigned short* __restrict__ qkvg,
    const float* __restrict__ bterm,
    const float* __restrict__ mask,
    unsigned short* __restrict__ opre)
{
    __shared__ unsigned short Kl[320][40];      // K rows [j][dc]
    __shared__ unsigned short VT[32][NPAD];     // V transposed [dc][j]
    __shared__ float mb[320];
    __shared__ int allone;
    int bid = blockIdx.x;
    int m = bid >> 2, h = bid & 3;
    int t = threadIdx.x;
    size_t base = (size_t)m * NRES * 512;
    if (t == 0) allone = 1;
    __syncthreads();
    for (int idx = t; idx < NRES * 4; idx += 320) {
        int row = idx >> 2, q = idx & 3;
        *(bf16x8*)(&Kl[row][q * 8]) =
            *(const bf16x8*)(qkvg + base + (size_t)row * 512 + 128 + h * 32 + q * 8);
    }
    {
        int dc = t & 31, jg = t >> 5;   // jg in 0..9, 32 cols each
        #pragma unroll 8
        for (int jj = 0; jj < 32; jj += 2) {
            int j = jg * 32 + jj;
            unsigned short v0 = qkvg[base + (size_t)j * 512 + 256 + h * 32 + dc];
            unsigned short v1 = qkvg[base + (size_t)(j + 1) * 512 + 256 + h * 32 + dc];
            *(unsigned int*)(&VT[dc][j]) = (unsigned int)v0 | ((unsigned int)v1 << 16);
        }
    }
    if (t < NRES) {
        float mmv = (100000.0f * LOG2E) * (mask[(size_t)m * NRES + t] - 1.0f);
        mb[t] = mmv;
        if (mmv != 0.0f) allone = 0;
    }
    __syncthreads();
    bool nomask = (allone != 0);

    int wave = t >> 6, lane = t & 63;
    int il = lane & 31;
    bool hi = (lane >= 32);
    int hi8 = hi ? 8 : 0, hi4 = hi ? 4 : 0;
    for (int c = 0; c < 2; ++c) {
        int i = (wave * 2 + c) * 32 + il;       // this lane's query row
        size_t qrow = base + (size_t)i * 512;
        bf16x8 qf1 = *(const bf16x8*)(qkvg + qrow + h * 32 + hi8);
        bf16x8 qf2 = *(const bf16x8*)(qkvg + qrow + h * 32 + 16 + hi8);
        const float* brow = bterm + (size_t)h * NN + (size_t)i * NRES;
        f32x16 O, z16;
        #pragma unroll
        for (int r = 0; r < 16; ++r) { O[r] = 0.0f; z16[r] = 0.0f; }
        float mrun = -3.0e38f, sum = 0.0f;
        #pragma unroll 1
        for (int kb = 0; kb < 10; ++kb) {
            int j0 = kb * 32;
            bf16x8 kf1 = *(const bf16x8*)(&Kl[j0 + il][hi8]);
            bf16x8 kf2 = *(const bf16x8*)(&Kl[j0 + il][16 + hi8]);
            f32x16 S = __builtin_amdgcn_mfma_f32_32x32x16_bf16(kf1, qf1, z16, 0, 0, 0);
            S = __builtin_amdgcn_mfma_f32_32x32x16_bf16(kf2, qf2, S, 0, 0, 0);
            // bias (+ mask) add; reg r -> j_local = (r&3) + 8*(r>>2) + 4*hi
            float mx = mrun;
            #pragma unroll
            for (int rg = 0; rg < 4; ++rg) {
                float4 bb = *(const float4*)(brow + j0 + rg * 8 + hi4);
                if (!nomask) {
                    float4 mm = *(const float4*)(&mb[j0 + rg * 8 + hi4]);
                    bb.x += mm.x; bb.y += mm.y; bb.z += mm.z; bb.w += mm.w;
                }
                S[rg * 4 + 0] += bb.x; S[rg * 4 + 1] += bb.y;
                S[rg * 4 + 2] += bb.z; S[rg * 4 + 3] += bb.w;
                mx = fmaxf(mx, fmaxf(fmaxf(S[rg * 4 + 0], S[rg * 4 + 1]),
                                     fmaxf(S[rg * 4 + 2], S[rg * 4 + 3])));
            }
            mx = fmaxf(mx, __shfl_xor(mx, 32, 64));   // combine with partner half-row
            if (kb) {
                float corr = __builtin_amdgcn_exp2f(mrun - mx);
                sum *= corr;
                #pragma unroll
                for (int r = 0; r < 16; ++r) O[r] *= corr;
            }
            mrun = mx;
            #pragma unroll
            for (int r = 0; r < 16; ++r) S[r] = __builtin_amdgcn_exp2f(S[r] - mx);
            #pragma unroll
            for (int r = 0; r < 16; r += 4)
                sum += (S[r] + S[r + 1]) + (S[r + 2] + S[r + 3]);
            // pack: w0..w7 ; w[p] = (reg 2p, reg 2p+1)
            unsigned int w0 = pk2bf(S[0], S[1]),   w1 = pk2bf(S[2], S[3]);
            unsigned int w2 = pk2bf(S[4], S[5]),   w3 = pk2bf(S[6], S[7]);
            unsigned int w4 = pk2bf(S[8], S[9]),   w5 = pk2bf(S[10], S[11]);
            unsigned int w6 = pk2bf(S[12], S[13]), w7 = pk2bf(S[14], S[15]);
            // redistribute: frag1 (j 0..15), frag2 (j 16..31)
            unsigned int v02 = hi ? w0 : w2; v02 = (unsigned int)__shfl_xor((int)v02, 32, 64);
            unsigned int v13 = hi ? w1 : w3; v13 = (unsigned int)__shfl_xor((int)v13, 32, 64);
            unsigned int v46 = hi ? w4 : w6; v46 = (unsigned int)__shfl_xor((int)v46, 32, 64);
            unsigned int v57 = hi ? w5 : w7; v57 = (unsigned int)__shfl_xor((int)v57, 32, 64);
            union { unsigned int u[4]; bf16x8 v; } f1, f2;
            f1.u[0] = hi ? v02 : w0;  f1.u[1] = hi ? v13 : w1;
            f1.u[2] = hi ? w2 : v02;  f1.u[3] = hi ? w3 : v13;
            f2.u[0] = hi ? v46 : w4;  f2.u[1] = hi ? v57 : w5;
            f2.u[2] = hi ? w6 : v46;  f2.u[3] = hi ? w7 : v57;
            bf16x8 vf1 = *(const bf16x8*)(&VT[il][j0 + hi8]);
            bf16x8 vf2 = *(const bf16x8*)(&VT[il][j0 + 16 + hi8]);
            O = __builtin_amdgcn_mfma_f32_32x32x16_bf16(vf1, f1.v, O, 0, 0, 0);
            O = __builtin_amdgcn_mfma_f32_32x32x16_bf16(vf2, f2.v, O, 0, 0, 0);
        }
        sum += __shfl_xor(sum, 32, 64);
        float inv = 1.0f / sum;
        size_t orow = ((size_t)m * NRES + i) * CCH + h * 32;
        #pragma unroll
        for (int rg = 0; rg < 4; ++rg) {
            int dcb = rg * 8 + hi4;
            u16x4 gv = *(const u16x4*)(qkvg + qrow + 384 + h * 32 + dcb);
            u16x4 ov;
            #pragma unroll
            for (int q = 0; q < 4; ++q) ov[q] = f2bf(O[rg * 4 + q] * inv * bf2f(gv[q]));
            *(u16x4*)(opre + orow + dcb) = ov;
        }
    }
}

// ---------------- Kernel 4: out = opre @ wo + bo (f32 out; conflict-free B staging) ----------------
__global__ __launch_bounds__(256) void k_out(
    const unsigned short* __restrict__ opre, const float* __restrict__ wo,
    const float* __restrict__ bo, float* __restrict__ out)
{
    __shared__ unsigned short A[128][136];
    __shared__ unsigned short Bt[128][136];
    int m0 = blockIdx.x * 128;
    int t = threadIdx.x;
    #pragma unroll
    for (int it = 0; it < 8; ++it) {
        int idx = it * 256 + t;
        int row = idx >> 4, chunk = idx & 15;
        *(bf16x8*)(&A[row][chunk * 8]) = *(const bf16x8*)(opre + (size_t)(m0 + row) * CCH + chunk * 8);
    }
    {
        int n = t & 127, p = t >> 7;
        const float* col = wo + n;
        #pragma unroll
        for (int q = 0; q < 8; ++q) {
            int k0 = p * 64 + q * 8;
            union { unsigned int u[4]; bf16x8 v; } pk;
            #pragma unroll
            for (int z = 0; z < 4; ++z)
                pk.u[z] = pk2bf(col[(size_t)(k0 + 2 * z) * 128], col[(size_t)(k0 + 2 * z + 1) * 128]);
            *(bf16x8*)(&Bt[n][k0]) = pk.v;
        }
    }
    __syncthreads();
    int wave = t >> 6, lane = t & 63;
    int wr = (wave >> 1) * 64, wc = (wave & 1) * 64;
    int li = lane & 15, lk = (lane >> 4) * 8;
    f32x4 acc[4][4] = {};
    #pragma unroll
    for (int kk = 0; kk < 4; ++kk) {
        bf16x8 af[4], bfr[4];
        #pragma unroll
        for (int i = 0; i < 4; ++i) af[i] = *(const bf16x8*)(&A[wr + i * 16 + li][kk * 32 + lk]);
        #pragma unroll
        for (int j = 0; j < 4; ++j) bfr[j] = *(const bf16x8*)(&Bt[wc + j * 16 + li][kk * 32 + lk]);
        __builtin_amdgcn_s_setprio(1);
        #pragma unroll
        for (int i = 0; i < 4; ++i)
            #pragma unroll
            for (int j = 0; j < 4; ++j)
                acc[i][j] = __builtin_amdgcn_mfma_f32_16x16x32_bf16(af[i], bfr[j], acc[i][j], 0, 0, 0);
        __builtin_amdgcn_s_setprio(0);
    }
    int rbase = (lane >> 4) * 4;
    #pragma unroll
    for (int i = 0; i < 4; ++i) {
        #pragma unroll
        for (int j = 0; j < 4; ++j) {
            int col = wc + j * 16 + li;
            #pragma unroll
            for (int r = 0; r < 4; ++r) {
                int grow = m0 + wr + i * 16 + rbase + r;
                out[(size_t)grow * CCH + col] = acc[i][j][r] + bo[col];
            }
        }
    }
}

extern "C" void kernel_launch(void* const* d_in, const int* in_sizes, int n_in,
                              void* d_out, int out_size, void* d_ws, size_t ws_size,
                              hipStream_t stream) {
    const float* x2d  = (const float*)d_in[0];
    const float* mask = (const float*)d_in[1];
    const float* ln_g = (const float*)d_in[2];
    const float* ln_b = (const float*)d_in[3];
    const float* wq   = (const float*)d_in[4];
    const float* wk   = (const float*)d_in[5];
    const float* wv   = (const float*)d_in[6];
    const float* wb   = (const float*)d_in[7];
    const float* wg   = (const float*)d_in[8];
    const float* bg   = (const float*)d_in[9];
    const float* wo   = (const float*)d_in[10];
    const float* bo   = (const float*)d_in[11];
    float* out = (float*)d_out;

    char* ws = (char*)d_ws;
    unsigned short* xn    = (unsigned short*)ws;                                 // 26,214,400 B (reused as opre)
    unsigned short* qkvg  = (unsigned short*)(ws + 26214400);                    // 104,857,600 B
    float*          bterm = (float*)(ws + 26214400 + 104857600);                 // 1,638,400 B
    unsigned short* opre  = xn;

    if (ws_size < (size_t)(26214400 + 104857600 + 1638400)) return;

    k_ln_bias<<<25600, 256, 0, stream>>>(x2d, ln_g, ln_b, wb, xn, bterm);
    k_proj<<<dim3(800, 4), 256, 0, stream>>>(xn, wq, wk, wv, wg, bg, qkvg);
    k_attn<<<1280, 320, 0, stream>>>(qkvg, bterm, mask, opre);
    k_out<<<800, 256, 0, stream>>>(opre, wo, bo, out);
}